// Round 8
// baseline (845.296 us; speedup 1.0000x reference)
//
#include <hip/hip_runtime.h>
#include <hip/hip_bf16.h>
#include <stdint.h>

#define B_SZ  16
#define S_SZ  2048
#define D_SZ  1024
#define FF_SZ 4096
#define DT_SZ 512

typedef __bf16 bf16x8 __attribute__((ext_vector_type(8)));
typedef float  f32x4  __attribute__((ext_vector_type(4)));
typedef short  short8 __attribute__((ext_vector_type(8)));

__device__ __forceinline__ short f2bf(float x) {
    union { float f; uint32_t u; } v; v.f = x;
    uint32_t r = (v.u + 0x7fffu + ((v.u >> 16) & 1u)) >> 16;  // RNE
    return (short)(uint16_t)r;
}

// ---------------- cast f32 -> bf16, 8 elems/thread ----------------
__global__ void cast_x_kernel(const float* __restrict__ src, short* __restrict__ dst, int n8) {
    int i = blockIdx.x * 256 + threadIdx.x;
    if (i >= n8) return;
    const float4* s4 = reinterpret_cast<const float4*>(src);
    float4 a = s4[2 * i], b = s4[2 * i + 1];
    short8 v;
    v[0] = f2bf(a.x); v[1] = f2bf(a.y); v[2] = f2bf(a.z); v[3] = f2bf(a.w);
    v[4] = f2bf(b.x); v[5] = f2bf(b.y); v[6] = f2bf(b.z); v[7] = f2bf(b.w);
    reinterpret_cast<short8*>(dst)[i] = v;
}

// ---------------- transpose + cast: src f32 [R][C] -> dst bf16 [C][R] ----------------
__global__ void transpose_cast_kernel(const float* __restrict__ src, short* __restrict__ dst,
                                      int R, int C) {
    __shared__ float tile[32][33];
    int c0 = blockIdx.x * 32, r0 = blockIdx.y * 32;
    int tx = threadIdx.x, ty = threadIdx.y;   // 32 x 8
#pragma unroll
    for (int i = 0; i < 32; i += 8)
        tile[ty + i][tx] = src[(size_t)(r0 + ty + i) * C + (c0 + tx)];
    __syncthreads();
#pragma unroll
    for (int i = 0; i < 32; i += 8)
        dst[(size_t)(c0 + ty + i) * R + (r0 + tx)] = f2bf(tile[tx][ty + i]);
}

// =====================================================================
// 128x128-tile bf16 GEMM: C = A(MxK) * Bt(NxK)^T
// 256 threads = 4 waves (2M x 2N), BK=32, 4-slot LDS ring (64 KB total
// -> 2 blocks/CU: cross-block wave overlap hides LDS/sync under MFMA,
// the m114/m97 mechanism). One barrier per K-tile, counted vmcnt
// (never 0 in steady state), XOR-swizzled LDS (0 bank conflicts),
// inverse-swizzled global_load_lds staging, setprio on MFMA cluster.
// =====================================================================

#define GLOAD(srcp, dstofs)                                                   \
    __builtin_amdgcn_global_load_lds(                                         \
        (__attribute__((address_space(1))) void*)(srcp),                      \
        (__attribute__((address_space(3))) void*)(ldsb + (dstofs)), 16, 0, 0)

#define WSLOT(S) (((S) + 3) & 3)

// One K-tile: slot S (literal 0..3), entry wait NW (literal), STG bool,
// TT = K-tile index being computed (stages tile TT+3 when STG).
#define TILE(S, NW, STG, TT) do {                                                           \
    asm volatile("s_waitcnt vmcnt(" #NW ")" ::: "memory");                                  \
    __builtin_amdgcn_s_barrier();                                                           \
    asm volatile("" ::: "memory");                                                          \
    __builtin_amdgcn_sched_barrier(0);                                                      \
    bf16x8 af[4], bfv[4];                                                                   \
    _Pragma("unroll")                                                                       \
    for (int ni = 0; ni < 4; ++ni)                                                          \
        bfv[ni] = *reinterpret_cast<const bf16x8*>(ldsb + (S) * 16384 + offB[ni]);          \
    _Pragma("unroll")                                                                       \
    for (int mi = 0; mi < 4; ++mi)                                                          \
        af[mi] = *reinterpret_cast<const bf16x8*>(ldsb + (S) * 16384 + offA[mi]);           \
    if (STG) {                                                                              \
        GLOAD(gA0 + (size_t)(TT + 3) * 32, WSLOT(S) * 16384 +         w * 1024);            \
        GLOAD(gA1 + (size_t)(TT + 3) * 32, WSLOT(S) * 16384 +  4096 + w * 1024);            \
        GLOAD(gB0 + (size_t)(TT + 3) * 32, WSLOT(S) * 16384 +  8192 + w * 1024);            \
        GLOAD(gB1 + (size_t)(TT + 3) * 32, WSLOT(S) * 16384 + 12288 + w * 1024);            \
    }                                                                                       \
    __builtin_amdgcn_s_setprio(1);                                                          \
    _Pragma("unroll")                                                                       \
    for (int mi = 0; mi < 4; ++mi)                                                          \
        _Pragma("unroll")                                                                   \
        for (int ni = 0; ni < 4; ++ni)                                                      \
            acc[mi][ni] = __builtin_amdgcn_mfma_f32_16x16x32_bf16(af[mi], bfv[ni],          \
                                                                  acc[mi][ni], 0, 0, 0);    \
    __builtin_amdgcn_s_setprio(0);                                                          \
} while (0)

template <bool GELU_BF16>
__global__ __launch_bounds__(256, 2)
void gemm128_kernel(const short* __restrict__ A, const short* __restrict__ Bt,
                    void* __restrict__ Cout, int M, int N, int K) {
    __shared__ char lds4[4][16384];   // slot: A tile [128][32]bf16 @0, B tile @8192
    char* ldsb = &lds4[0][0];

    const int tid = threadIdx.x;
    const int w   = tid >> 6;      // 0..3
    const int l   = tid & 63;
    const int wm  = w >> 1;        // 0..1
    const int wn  = w & 1;         // 0..1
    const int kq  = l >> 4;        // 0..3
    const int l15 = l & 15;

    // XCD-bijective block swizzle (grids are multiples of 8 by construction)
    const int nwg = gridDim.x;
    int swzw = blockIdx.x;
    if ((nwg & 7) == 0) swzw = (swzw & 7) * (nwg >> 3) + (swzw >> 3);
    const int MB = M >> 7;
    const int bm = swzw % MB, bn = swzw / MB;
    const int m0 = bm << 7, n0 = bn << 7;

    // ---- loop-invariant swizzled ds_read byte offsets (registers) ----
    // logical byte = row*64 + kq*16 ; phys = logical ^ (((row>>1)&7)<<4)
    int offA[4], offB[4];
#pragma unroll
    for (int mi = 0; mi < 4; ++mi) {
        const int r = wm * 64 + mi * 16 + l15;
        offA[mi] = (r * 64 + kq * 16) ^ (((r >> 1) & 7) << 4);
    }
#pragma unroll
    for (int ni = 0; ni < 4; ++ni) {
        const int r = wn * 64 + ni * 16 + l15;
        offB[ni] = 8192 + ((r * 64 + kq * 16) ^ (((r >> 1) & 7) << 4));
    }

    // ---- staging source addresses (inverse-swizzled global, linear LDS dest) ----
    // per 4KB sweep: thread writes LDS byte X; logical P = X ^ (((X>>7)&7)<<4);
    // row = P>>6 (64B rows), col elems = (P&63)>>1.
    const int X0 = tid * 16;
    const int P0 = X0 ^ (((X0 >> 7) & 7) << 4);
    const int r0_ = P0 >> 6, c0_ = (P0 & 63) >> 1;    // rows 0..63
    const int X1 = 4096 + tid * 16;
    const int P1 = X1 ^ (((X1 >> 7) & 7) << 4);
    const int r1_ = P1 >> 6, c1_ = (P1 & 63) >> 1;    // rows 64..127
    const short* gA0 = A  + (size_t)(m0 + r0_) * K + c0_;
    const short* gA1 = A  + (size_t)(m0 + r1_) * K + c1_;
    const short* gB0 = Bt + (size_t)(n0 + r0_) * K + c0_;
    const short* gB1 = Bt + (size_t)(n0 + r1_) * K + c1_;

    f32x4 acc[4][4];
#pragma unroll
    for (int mi = 0; mi < 4; ++mi)
#pragma unroll
        for (int ni = 0; ni < 4; ++ni)
            acc[mi][ni] = (f32x4){0.f, 0.f, 0.f, 0.f};

    const int NT = K >> 5;            // K-tiles of 32 (multiple of 4 for our shapes)

    // prologue: tiles 0,1,2 in flight (12 loads; order A0,A1,B0,B1 per tile)
#pragma unroll
    for (int x = 0; x < 3; ++x) {
        GLOAD(gA0 + x * 32, x * 16384 +         w * 1024);
        GLOAD(gA1 + x * 32, x * 16384 +  4096 + w * 1024);
        GLOAD(gB0 + x * 32, x * 16384 +  8192 + w * 1024);
        GLOAD(gB1 + x * 32, x * 16384 + 12288 + w * 1024);
    }

    int t = 0;
    for (; t + 8 <= NT; t += 4) {     // steady state: 12 loads in flight at entry
        TILE(0, 8, true, t);
        TILE(1, 8, true, t + 1);
        TILE(2, 8, true, t + 2);
        TILE(3, 8, true, t + 3);
    }
    // final group (t == NT-4): stage last tile, then drain 8 -> 4 -> 0
    TILE(0, 8, true,  t);
    TILE(1, 8, false, t + 1);
    TILE(2, 4, false, t + 2);
    TILE(3, 0, false, t + 3);

    // epilogue — D layout (m89): col = lane&15, row = (lane>>4)*4 + reg
    const int row_base = m0 + wm * 64 + kq * 4;
    const int col_base = n0 + wn * 64 + l15;
    if constexpr (GELU_BF16) {
        short* C = reinterpret_cast<short*>(Cout);
#pragma unroll
        for (int mi = 0; mi < 4; ++mi)
#pragma unroll
            for (int r = 0; r < 4; ++r) {
                const size_t ro = (size_t)(row_base + mi * 16 + r) * N;
#pragma unroll
                for (int ni = 0; ni < 4; ++ni) {
                    float x = acc[mi][ni][r];
                    float u = 0.7978845608028654f * (x + 0.044715f * x * x * x);
                    float g = x / (1.f + __expf(-2.f * u));
                    C[ro + col_base + ni * 16] = f2bf(g);
                }
            }
    } else {
        float* C = reinterpret_cast<float*>(Cout);
#pragma unroll
        for (int mi = 0; mi < 4; ++mi)
#pragma unroll
            for (int r = 0; r < 4; ++r) {
                const size_t ro = (size_t)(row_base + mi * 16 + r) * N;
#pragma unroll
                for (int ni = 0; ni < 4; ++ni)
                    C[ro + col_base + ni * 16] = acc[mi][ni][r];
            }
    }
}

// ---------------- intervention: out[b, eot[b], 0:512] = row[0:512] @ Wrot @ Winv ----------------
__global__ void intervention_kernel(const float* __restrict__ Wrot, const float* __restrict__ Winv,
                                    const int* __restrict__ eot, float* __restrict__ out) {
    __shared__ float tgt[DT_SZ];
    __shared__ float tmp[DT_SZ];
    const int b = blockIdx.x;
    const int j = threadIdx.x;
    float* row = out + ((size_t)b * S_SZ + eot[b]) * D_SZ;
    tgt[j] = row[j];                      // ST=0 slice
    __syncthreads();
    float s = 0.f;
#pragma unroll 8
    for (int i = 0; i < DT_SZ; ++i) s = fmaf(tgt[i], Wrot[(size_t)i * DT_SZ + j], s);
    tmp[j] = s;
    __syncthreads();
    float s2 = 0.f;
#pragma unroll 8
    for (int i = 0; i < DT_SZ; ++i) s2 = fmaf(tmp[i], Winv[(size_t)i * DT_SZ + j], s2);
    row[j] = s2;
}

extern "C" void kernel_launch(void* const* d_in, const int* in_sizes, int n_in,
                              void* d_out, int out_size, void* d_ws, size_t ws_size,
                              hipStream_t stream) {
    const float* hidden = (const float*)d_in[0];
    const float* W1     = (const float*)d_in[1];
    const float* W2     = (const float*)d_in[2];
    const float* Wrot   = (const float*)d_in[3];
    const float* Winv   = (const float*)d_in[4];
    const int*   eot    = (const int*)d_in[5];
    float* out = (float*)d_out;

    const int M = B_SZ * S_SZ;   // 32768

    // ws layout: W1t (FF x D bf16) | W2t (D x FF bf16) | Xbf chunk | C1 chunk
    short* W1t = (short*)d_ws;
    short* W2t = W1t + (size_t)FF_SZ * D_SZ;
    short* Xbf = W2t + (size_t)FF_SZ * D_SZ;
    const size_t fixed_bytes = 2ull * (size_t)FF_SZ * D_SZ * sizeof(short);  // 16 MiB
    const size_t per_row = (size_t)D_SZ * 2 + (size_t)FF_SZ * 2;             // 10240 B
    size_t rem = ws_size > fixed_bytes ? ws_size - fixed_bytes : 0;
    int Mc = (int)(rem / per_row);
    Mc = (Mc / 512) * 512;       // keeps every grid a multiple of 8
    if (Mc < 512) Mc = 512;
    if (Mc > M) Mc = M;
    short* C1 = Xbf + (size_t)Mc * D_SZ;

    transpose_cast_kernel<<<dim3(FF_SZ / 32, D_SZ / 32), dim3(32, 8), 0, stream>>>(W1, W1t, D_SZ, FF_SZ);
    transpose_cast_kernel<<<dim3(D_SZ / 32, FF_SZ / 32), dim3(32, 8), 0, stream>>>(W2, W2t, FF_SZ, D_SZ);

    for (int ms = 0; ms < M; ms += Mc) {
        const int mc = (M - ms < Mc) ? (M - ms) : Mc;   // multiple of 512
        const int n8 = mc * D_SZ / 8;
        cast_x_kernel<<<(n8 + 255) / 256, 256, 0, stream>>>(hidden + (size_t)ms * D_SZ, Xbf, n8);
        gemm128_kernel<true ><<<dim3((mc / 128) * (FF_SZ / 128)), 256, 0, stream>>>(
            Xbf, W1t, C1, mc, FF_SZ, D_SZ);
        gemm128_kernel<false><<<dim3((mc / 128) * (D_SZ / 128)), 256, 0, stream>>>(
            C1, W2t, out + (size_t)ms * D_SZ, mc, D_SZ, FF_SZ);
    }
    intervention_kernel<<<B_SZ, DT_SZ, 0, stream>>>(Wrot, Winv, eot, out);
}

// Round 9
// 672.352 us; speedup vs baseline: 1.2572x; 1.2572x over previous
//
#include <hip/hip_runtime.h>
#include <hip/hip_bf16.h>
#include <stdint.h>

#define B_SZ  16
#define S_SZ  2048
#define D_SZ  1024
#define FF_SZ 4096
#define DT_SZ 512

typedef __bf16 bf16x8 __attribute__((ext_vector_type(8)));
typedef float  f32x4  __attribute__((ext_vector_type(4)));
typedef short  short8 __attribute__((ext_vector_type(8)));

__device__ __forceinline__ short f2bf(float x) {
    union { float f; uint32_t u; } v; v.f = x;
    uint32_t r = (v.u + 0x7fffu + ((v.u >> 16) & 1u)) >> 16;  // RNE
    return (short)(uint16_t)r;
}

// ---------------- cast f32 -> bf16, 8 elems/thread ----------------
__global__ void cast_x_kernel(const float* __restrict__ src, short* __restrict__ dst, int n8) {
    int i = blockIdx.x * 256 + threadIdx.x;
    if (i >= n8) return;
    const float4* s4 = reinterpret_cast<const float4*>(src);
    float4 a = s4[2 * i], b = s4[2 * i + 1];
    short8 v;
    v[0] = f2bf(a.x); v[1] = f2bf(a.y); v[2] = f2bf(a.z); v[3] = f2bf(a.w);
    v[4] = f2bf(b.x); v[5] = f2bf(b.y); v[6] = f2bf(b.z); v[7] = f2bf(b.w);
    reinterpret_cast<short8*>(dst)[i] = v;
}

// ---------------- transpose + cast: src f32 [R][C] -> dst bf16 [C][R] ----------------
__global__ void transpose_cast_kernel(const float* __restrict__ src, short* __restrict__ dst,
                                      int R, int C) {
    __shared__ float tile[32][33];
    int c0 = blockIdx.x * 32, r0 = blockIdx.y * 32;
    int tx = threadIdx.x, ty = threadIdx.y;   // 32 x 8
#pragma unroll
    for (int i = 0; i < 32; i += 8)
        tile[ty + i][tx] = src[(size_t)(r0 + ty + i) * C + (c0 + tx)];
    __syncthreads();
#pragma unroll
    for (int i = 0; i < 32; i += 8)
        dst[(size_t)(c0 + ty + i) * R + (r0 + tx)] = f2bf(tile[tx][ty + i]);
}

// =====================================================================
// 256x256-tile bf16 GEMM, m201 8-phase template port.
// BK=64, double-buffered LDS (2 x {A[256][64], B[256][64]} = 128 KiB),
// 8 waves (2M x 4N), per-wave C 128x64 (acc 8x4 of 16x16).
// Per K-step: 4 phases x 16 MFMA; reads split 8/4/8/4 ds_read_b128.
// Staging in 128-row HALF-tiles, 2 global_load_lds/thread/phase, rotated
// so each half is staged exactly one phase after its last reader's
// lgkmcnt(0)+barrier (WAR-safe). vmcnt(2) only at phases 4 and 8,
// placed BEFORE the trailing barrier (cross-wave RAW-safe).
// Swizzle (128B rows): phys = row*128 + ((slot ^ (row&7))<<4) — 0-conflict.
// =====================================================================

#define GLOAD(srcp, dstofs)                                                   \
    __builtin_amdgcn_global_load_lds(                                         \
        (__attribute__((address_space(1))) void*)(srcp),                      \
        (__attribute__((address_space(3))) void*)(ldsb + (dstofs)), 16, 0, 0)

#define ABASE(S) ((S) * 65536)
#define BBASE(S) ((S) * 65536 + 32768)

// stage half H of operand into buffer slot S for K-step T (2 loads/thread)
#define STG_A(S, H, T) do {                                                                 \
    GLOAD(gA[H][0] + (size_t)(T) * 64, ABASE(S) + (H) * 16384 +        w * 1024);           \
    GLOAD(gA[H][1] + (size_t)(T) * 64, ABASE(S) + (H) * 16384 + 8192 + w * 1024);           \
} while (0)
#define STG_B(S, H, T) do {                                                                 \
    GLOAD(gB[H][0] + (size_t)(T) * 64, BBASE(S) + (H) * 16384 +        w * 1024);           \
    GLOAD(gB[H][1] + (size_t)(T) * 64, BBASE(S) + (H) * 16384 + 8192 + w * 1024);           \
} while (0)
#define NOSTG ((void)0)
#define VM2  asm volatile("s_waitcnt vmcnt(2)" ::: "memory")
#define VM0  asm volatile("s_waitcnt vmcnt(0)" ::: "memory")
#define NOVM ((void)0)

// One phase: slot S, k-slice KS (0/1), mi-group MIG (0/1), RB=read B frags,
// VM at end (before trailing barrier), __VA_ARGS__ = stage statement.
#define PHASE(S, KS, MIG, RB, VM, ...) do {                                                 \
    if (RB) {                                                                               \
        _Pragma("unroll")                                                                   \
        for (int ni = 0; ni < 4; ++ni)                                                      \
            bfv[ni] = *reinterpret_cast<const bf16x8*>(                                     \
                ldsb + BBASE(S) + (offB[ni] ^ ((KS) * 64)));                                \
    }                                                                                       \
    _Pragma("unroll")                                                                       \
    for (int mi = 0; mi < 4; ++mi)                                                          \
        af[mi] = *reinterpret_cast<const bf16x8*>(                                          \
            ldsb + ABASE(S) + (offA[(MIG) * 4 + mi] ^ ((KS) * 64)));                        \
    __VA_ARGS__;                                                                            \
    __builtin_amdgcn_s_barrier();                                                           \
    asm volatile("s_waitcnt lgkmcnt(0)" ::: "memory");                                      \
    __builtin_amdgcn_sched_barrier(0);                                                      \
    __builtin_amdgcn_s_setprio(1);                                                          \
    _Pragma("unroll")                                                                       \
    for (int mi = 0; mi < 4; ++mi)                                                          \
        _Pragma("unroll")                                                                   \
        for (int ni = 0; ni < 4; ++ni)                                                      \
            acc[(MIG) * 4 + mi][ni] = __builtin_amdgcn_mfma_f32_16x16x32_bf16(              \
                af[mi], bfv[ni], acc[(MIG) * 4 + mi][ni], 0, 0, 0);                         \
    __builtin_amdgcn_s_setprio(0);                                                          \
    __builtin_amdgcn_sched_barrier(0);                                                      \
    VM;                                                                                     \
    __builtin_amdgcn_s_barrier();                                                           \
} while (0)

// Steady iteration: computes K-steps T (slot0) and T+1 (slot1);
// stages T+1's remaining halves (P1-3), T+2 (P4-7), T+3's Bh0 (P8).
#define ITER_FULL(T) do {                                                                   \
    PHASE(0, 0, 0, 1, NOVM, STG_B(1, 1, (T) + 1));                                          \
    PHASE(0, 0, 1, 0, NOVM, STG_A(1, 0, (T) + 1));                                          \
    PHASE(0, 1, 0, 1, NOVM, STG_A(1, 1, (T) + 1));                                          \
    PHASE(0, 1, 1, 0, VM2,  STG_B(0, 0, (T) + 2));                                          \
    PHASE(1, 0, 0, 1, NOVM, STG_B(0, 1, (T) + 2));                                          \
    PHASE(1, 0, 1, 0, NOVM, STG_A(0, 0, (T) + 2));                                          \
    PHASE(1, 1, 0, 1, NOVM, STG_A(0, 1, (T) + 2));                                          \
    PHASE(1, 1, 1, 0, VM2,  STG_B(1, 0, (T) + 3));                                          \
} while (0)

// Last iteration (T = NT-2): stage only T+1's halves; drain with vmcnt(0).
#define ITER_LAST(T) do {                                                                   \
    PHASE(0, 0, 0, 1, NOVM, STG_B(1, 1, (T) + 1));                                          \
    PHASE(0, 0, 1, 0, NOVM, STG_A(1, 0, (T) + 1));                                          \
    PHASE(0, 1, 0, 1, NOVM, STG_A(1, 1, (T) + 1));                                          \
    PHASE(0, 1, 1, 0, VM0,  NOSTG);                                                         \
    PHASE(1, 0, 0, 1, NOVM, NOSTG);                                                         \
    PHASE(1, 0, 1, 0, NOVM, NOSTG);                                                         \
    PHASE(1, 1, 0, 1, NOVM, NOSTG);                                                         \
    PHASE(1, 1, 1, 0, NOVM, NOSTG);                                                         \
} while (0)

template <bool GELU_BF16>
__global__ __launch_bounds__(512, 2)
void gemm256_kernel(const short* __restrict__ A, const short* __restrict__ Bt,
                    void* __restrict__ Cout, int M, int N, int K) {
    __shared__ char lds2[2][65536];   // slot: A[256][64]bf16 @0, B @32768
    char* ldsb = &lds2[0][0];

    const int tid = threadIdx.x;
    const int w   = tid >> 6;
    const int l   = tid & 63;
    const int wm  = w >> 2;        // 0..1
    const int wn  = w & 3;         // 0..3
    const int kq  = l >> 4;        // 0..3
    const int l15 = l & 15;

    // XCD-bijective block swizzle (grids are multiples of 8 by construction)
    const int nwg = gridDim.x;
    int swzw = blockIdx.x;
    if ((nwg & 7) == 0) swzw = (swzw & 7) * (nwg >> 3) + (swzw >> 3);
    const int MB = M >> 8;
    const int bm = swzw % MB, bn = swzw / MB;
    const int m0 = bm << 8, n0 = bn << 8;

    // ---- swizzled ds_read byte offsets for ks=0 (ks=1 = off ^ 64) ----
    // logical = row*128 + kq*16 ; phys = row*128 + ((kq ^ (row&7))<<4)
    int offA[8], offB[4];
#pragma unroll
    for (int mi = 0; mi < 8; ++mi) {
        const int r = wm * 128 + mi * 16 + l15;
        offA[mi] = r * 128 + ((kq ^ (r & 7)) << 4);
    }
#pragma unroll
    for (int ni = 0; ni < 4; ++ni) {
        const int r = wn * 64 + ni * 16 + l15;
        offB[ni] = r * 128 + ((kq ^ (r & 7)) << 4);
    }

    // ---- staging sources (inverse-swizzled global, linear LDS dest) ----
    // within a 16KB half: X = tid*16 + j*8192 ; P = X ^ (((X>>7)&7)<<4) ;
    // row = h*128 + (P>>7), col elems = (P&127)>>1
    const short *gA[2][2], *gB[2][2];
#pragma unroll
    for (int h = 0; h < 2; ++h)
#pragma unroll
        for (int j = 0; j < 2; ++j) {
            const int X = tid * 16 + j * 8192;
            const int P = X ^ (((X >> 7) & 7) << 4);
            const int r = P >> 7, c = (P & 127) >> 1;
            gA[h][j] = A  + (size_t)(m0 + h * 128 + r) * K + c;
            gB[h][j] = Bt + (size_t)(n0 + h * 128 + r) * K + c;
        }

    f32x4 acc[8][4];
#pragma unroll
    for (int mi = 0; mi < 8; ++mi)
#pragma unroll
        for (int ni = 0; ni < 4; ++ni)
            acc[mi][ni] = (f32x4){0.f, 0.f, 0.f, 0.f};

    bf16x8 af[4], bfv[4];
    const int NT = K >> 6;            // K-steps of 64 (even for our shapes)
    const int NI = NT >> 1;           // iterations (2 K-steps each)

    // prologue = virtual P4-P8 of iter -1: slot0 gets K-step 0, slot1 Bh0 of 1
    STG_B(0, 0, 0);
    STG_B(0, 1, 0);
    STG_A(0, 0, 0);
    STG_A(0, 1, 0);
    STG_B(1, 0, 1);
    VM2;                               // slot0's 4 halves landed
    __builtin_amdgcn_s_barrier();

    for (int i = 0; i < NI - 1; ++i) {
        const int T = 2 * i;
        ITER_FULL(T);
    }
    ITER_LAST(2 * (NI - 1));

    // epilogue — D layout (m89): col = lane&15, row = (lane>>4)*4 + reg
    const int row_base = m0 + wm * 128 + kq * 4;
    const int col_base = n0 + wn * 64 + l15;
    if constexpr (GELU_BF16) {
        short* C = reinterpret_cast<short*>(Cout);
#pragma unroll
        for (int mi = 0; mi < 8; ++mi)
#pragma unroll
            for (int r = 0; r < 4; ++r) {
                const size_t ro = (size_t)(row_base + mi * 16 + r) * N;
#pragma unroll
                for (int ni = 0; ni < 4; ++ni) {
                    float x = acc[mi][ni][r];
                    float u = 0.7978845608028654f * (x + 0.044715f * x * x * x);
                    float g = x / (1.f + __expf(-2.f * u));
                    C[ro + col_base + ni * 16] = f2bf(g);
                }
            }
    } else {
        float* C = reinterpret_cast<float*>(Cout);
#pragma unroll
        for (int mi = 0; mi < 8; ++mi)
#pragma unroll
            for (int r = 0; r < 4; ++r) {
                const size_t ro = (size_t)(row_base + mi * 16 + r) * N;
#pragma unroll
                for (int ni = 0; ni < 4; ++ni)
                    C[ro + col_base + ni * 16] = acc[mi][ni][r];
            }
    }
}

// ---------------- intervention: out[b, eot[b], 0:512] = row[0:512] @ Wrot @ Winv ----------------
__global__ void intervention_kernel(const float* __restrict__ Wrot, const float* __restrict__ Winv,
                                    const int* __restrict__ eot, float* __restrict__ out) {
    __shared__ float tgt[DT_SZ];
    __shared__ float tmp[DT_SZ];
    const int b = blockIdx.x;
    const int j = threadIdx.x;
    float* row = out + ((size_t)b * S_SZ + eot[b]) * D_SZ;
    tgt[j] = row[j];                      // ST=0 slice
    __syncthreads();
    float s = 0.f;
#pragma unroll 8
    for (int i = 0; i < DT_SZ; ++i) s = fmaf(tgt[i], Wrot[(size_t)i * DT_SZ + j], s);
    tmp[j] = s;
    __syncthreads();
    float s2 = 0.f;
#pragma unroll 8
    for (int i = 0; i < DT_SZ; ++i) s2 = fmaf(tmp[i], Winv[(size_t)i * DT_SZ + j], s2);
    row[j] = s2;
}

extern "C" void kernel_launch(void* const* d_in, const int* in_sizes, int n_in,
                              void* d_out, int out_size, void* d_ws, size_t ws_size,
                              hipStream_t stream) {
    const float* hidden = (const float*)d_in[0];
    const float* W1     = (const float*)d_in[1];
    const float* W2     = (const float*)d_in[2];
    const float* Wrot   = (const float*)d_in[3];
    const float* Winv   = (const float*)d_in[4];
    const int*   eot    = (const int*)d_in[5];
    float* out = (float*)d_out;

    const int M = B_SZ * S_SZ;   // 32768

    // ws layout: W1t (FF x D bf16) | W2t (D x FF bf16) | Xbf chunk | C1 chunk
    short* W1t = (short*)d_ws;
    short* W2t = W1t + (size_t)FF_SZ * D_SZ;
    short* Xbf = W2t + (size_t)FF_SZ * D_SZ;
    const size_t fixed_bytes = 2ull * (size_t)FF_SZ * D_SZ * sizeof(short);  // 16 MiB
    const size_t per_row = (size_t)D_SZ * 2 + (size_t)FF_SZ * 2;             // 10240 B
    size_t rem = ws_size > fixed_bytes ? ws_size - fixed_bytes : 0;
    int Mc = (int)(rem / per_row);
    Mc = (Mc / 512) * 512;       // keeps every grid a multiple of 8
    if (Mc < 512) Mc = 512;
    if (Mc > M) Mc = M;
    short* C1 = Xbf + (size_t)Mc * D_SZ;

    transpose_cast_kernel<<<dim3(FF_SZ / 32, D_SZ / 32), dim3(32, 8), 0, stream>>>(W1, W1t, D_SZ, FF_SZ);
    transpose_cast_kernel<<<dim3(D_SZ / 32, FF_SZ / 32), dim3(32, 8), 0, stream>>>(W2, W2t, FF_SZ, D_SZ);

    for (int ms = 0; ms < M; ms += Mc) {
        const int mc = (M - ms < Mc) ? (M - ms) : Mc;   // multiple of 512
        const int n8 = mc * D_SZ / 8;
        cast_x_kernel<<<(n8 + 255) / 256, 256, 0, stream>>>(hidden + (size_t)ms * D_SZ, Xbf, n8);
        gemm256_kernel<true ><<<dim3((mc / 256) * (FF_SZ / 256)), 512, 0, stream>>>(
            Xbf, W1t, C1, mc, FF_SZ, D_SZ);
        gemm256_kernel<false><<<dim3((mc / 256) * (D_SZ / 256)), 512, 0, stream>>>(
            C1, W2t, out + (size_t)ms * D_SZ, mc, D_SZ, FF_SZ);
    }
    intervention_kernel<<<B_SZ, DT_SZ, 0, stream>>>(Wrot, Winv, eot, out);
}